// Round 2
// baseline (406.407 us; speedup 1.0000x reference)
//
#include <hip/hip_runtime.h>
#include <hip/hip_cooperative_groups.h>

namespace cg = cooperative_groups;

#define LEN 4096
#define BATCH 32
#define CH 256
#define REPN 198
#define GHOSTN 58
#define NROW (REPN * BATCH)     /* 6336 */
#define NGHOST (GHOSTN * BATCH) /* 1856 */
#define NITEM (NROW + NGHOST)   /* 8192 = 8 * 1024 exactly */
#define GRID 1024
#define CPT 16                  /* outputs per thread in phase-1 stats */

typedef float f32x4 __attribute__((ext_vector_type(4)));

// ---------------------------------------------------------------------------
// COMPILE-TIME numpy-legacy RNG replication (verified in prior session):
// np.random.seed(123); np.random.choice(256, 58, replace=False)
// ---------------------------------------------------------------------------
struct MTState { unsigned mt[624]; int mti; };
struct Tab { int rep[REPN]; int ghost[GHOSTN]; };

static constexpr unsigned mt_next(MTState& s) {
    if (s.mti >= 624) {
        for (int k = 0; k < 624; ++k) {
            unsigned y = (s.mt[k] & 0x80000000u) | (s.mt[(k + 1) % 624] & 0x7fffffffu);
            s.mt[k] = s.mt[(k + 397) % 624] ^ (y >> 1) ^ ((y & 1u) ? 0x9908b0dfu : 0u);
        }
        s.mti = 0;
    }
    unsigned y = s.mt[s.mti++];
    y ^= y >> 11;
    y ^= (y << 7) & 0x9d2c5680u;
    y ^= (y << 15) & 0xefc60000u;
    y ^= y >> 18;
    return y;
}

static constexpr Tab make_tab() {
    MTState s{};
    s.mt[0] = 123u;
    for (int i = 1; i < 624; ++i)
        s.mt[i] = 1812433253u * (s.mt[i - 1] ^ (s.mt[i - 1] >> 30)) + (unsigned)i;
    s.mti = 624;
    int perm[256] = {};
    for (int i = 0; i < 256; ++i) perm[i] = i;
    for (int i = 255; i > 0; --i) {
        unsigned mask = (unsigned)i;
        mask |= mask >> 1; mask |= mask >> 2; mask |= mask >> 4;
        mask |= mask >> 8; mask |= mask >> 16;
        unsigned j = 0;
        do { j = mt_next(s) & mask; } while (j > (unsigned)i);
        int t = perm[i]; perm[i] = perm[j]; perm[j] = t;
    }
    bool g[256] = {};
    for (int k = 0; k < GHOSTN; ++k) g[perm[k]] = true;
    Tab t{};
    int rc = 0, gc = 0;
    for (int c = 0; c < 256; ++c) {
        if (g[c]) t.ghost[gc++] = c;
        else      t.rep[rc++] = c;
    }
    return t;
}

__constant__ Tab d_tab = make_tab();

// ---------------------------------------------------------------------------
// helpers
// ---------------------------------------------------------------------------
__device__ __forceinline__ const float* item_src(const float* __restrict__ x, int item) {
    int ch, b;
    if (item < NROW) {
        const int r = item % REPN; b = item / REPN; ch = d_tab.rep[r];
    } else {
        const int g = (item - NROW) % GHOSTN; b = (item - NROW) / GHOSTN; ch = d_tab.ghost[g];
    }
    return x + ((size_t)b * CH + ch) * LEN;
}

__device__ __forceinline__ void load_fast(const float* __restrict__ row, int e, float* v) {
    const f32x4* q4 = (const f32x4*)(row + e - 8);
#pragma unroll
    for (int t = 0; t < 5; ++t) {
        f32x4 u = q4[t];
        v[4 * t] = u.x; v[4 * t + 1] = u.y; v[4 * t + 2] = u.z; v[4 * t + 3] = u.w;
    }
}

__device__ __forceinline__ void load_slow(const float* __restrict__ row, int e, float* v) {
#pragma unroll
    for (int d = 0; d < 20; ++d) {
        int fi = e - 8 + d;
        v[d] = ((unsigned)fi < (unsigned)LEN) ? row[fi] : 0.f;
    }
}

// Device-scope (agent) atomic accessors for the cross-XCD-communicated stats.
// Per-XCD L2s are NOT coherent inside a single dispatch; plain loads can hit
// stale (poisoned) lines after grid.sync(). Atomics go to the coherence point.
__device__ __forceinline__ void stats_put(float* p, float v) {
    __hip_atomic_store(p, v, __ATOMIC_RELAXED, __HIP_MEMORY_SCOPE_AGENT);
}
__device__ __forceinline__ float stats_get(const float* p) {
    return __hip_atomic_load(p, __ATOMIC_RELAXED, __HIP_MEMORY_SCOPE_AGENT);
}

// ===========================================================================
// MODE 0: fused cooperative (phase1 -> grid.sync -> phase2)
// MODE 1: phase 1 only (fallback, normal launch)
// MODE 2: phase 2 only (fallback, normal launch)
// ===========================================================================
template <int MODE>
__global__ __launch_bounds__(256, 4) void fused_kernel(
    const float* __restrict__ x,
    const float* __restrict__ w1, const float* __restrict__ w2,
    float* __restrict__ stats_ws,
    const float* __restrict__ g1, const float* __restrict__ b1,
    const float* __restrict__ g2, const float* __restrict__ b2,
    const float* __restrict__ g3, const float* __restrict__ b3,
    float* __restrict__ out) {
    const int tid = threadIdx.x;

    if constexpr (MODE != 2) {
        __shared__ float s[2][LEN + 16];
        __shared__ float red[6][4];

        // halos zeroed once (never overwritten by stages)
        if (tid < 8) {
            s[0][tid] = 0.f; s[0][LEN + 8 + tid] = 0.f;
            s[1][tid] = 0.f; s[1][LEN + 8 + tid] = 0.f;
        }
        // prologue: stage item k=0 directly into buffer 0
        {
            const f32x4* row4 = (const f32x4*)item_src(x, blockIdx.x);
            f32x4* s4 = (f32x4*)(s[0] + 8);
#pragma unroll
            for (int t = 0; t < 4; ++t) s4[tid + 256 * t] = row4[tid + 256 * t];
        }
        __syncthreads();

#pragma unroll 1
        for (int k = 0; k < 8; ++k) {
            const int buf = k & 1;
            const int item = blockIdx.x + GRID * k;

            // T14 issue-early: next item's 16 KB into 4 f32x4 regs (latency
            // hides under the FIR compute below).
            f32x4 pf[4];
            if (k < 7) {
                const f32x4* row4 = (const f32x4*)item_src(x, blockIdx.x + GRID * (k + 1));
#pragma unroll
                for (int t = 0; t < 4; ++t) pf[t] = row4[tid + 256 * t];
            }

            if (item < NROW) {
                const int r = item % REPN;
                const int b = item / REPN;
                float w[5][3];
                {
                    const float* p1 = w1 + r * 15;
                    const float* p2 = w2 + r * 15;
#pragma unroll
                    for (int i = 0; i < 5; ++i)
#pragma unroll
                        for (int t = 0; t < 3; ++t) w[i][t] = p1[i * 3 + t] + p2[i * 3 + t];
                }
                const int l0 = tid * CPT;
                // Thread window: v[q] = row[l0 - 8 + q], 16B-aligned ds_read_b128 x8.
                float v[32];
                {
                    const f32x4* sw = (const f32x4*)(s[buf] + l0);
#pragma unroll
                    for (int q = 0; q < 8; ++q) {
                        f32x4 t = sw[q];
                        v[4 * q] = t.x; v[4 * q + 1] = t.y; v[4 * q + 2] = t.z; v[4 * q + 3] = t.w;
                    }
                }
                // FIR semantics (verified prior session):
                //   x1 group i: taps v[j+1+3i..j+3+3i], gated on 0 <= l-6+3i < LEN
                //   x2 group i: taps v[j+13-3i..j+15-3i], gated on 0 <= l+6-3i < LEN
                //   x3 = ungated group-2 partial of x1
                float s1 = 0, s1q = 0, s2 = 0, s2q = 0, s3 = 0, s3q = 0;
                const bool edge = (tid == 0) | (tid == 255);
#define STAT_BODY(GATED)                                                          \
    _Pragma("unroll")                                                             \
    for (int j = 0; j < CPT; ++j) {                                               \
        const int l = l0 + j;                                                     \
        float x1 = 0.f, x2 = 0.f, x3 = 0.f;                                       \
        _Pragma("unroll")                                                         \
        for (int i = 0; i < 5; ++i) {                                             \
            float a1 = fmaf(w[i][0], v[j + 1 + 3 * i],                            \
                       fmaf(w[i][1], v[j + 2 + 3 * i],                            \
                            w[i][2] * v[j + 3 + 3 * i]));                         \
            float a2 = fmaf(w[i][0], v[j + 13 - 3 * i],                           \
                       fmaf(w[i][1], v[j + 14 - 3 * i],                           \
                            w[i][2] * v[j + 15 - 3 * i]));                        \
            if (i == 2) x3 = a1; /* ungated */                                    \
            if (GATED) {                                                          \
                a1 = ((unsigned)(l - 6 + 3 * i) < (unsigned)LEN) ? a1 : 0.f;      \
                a2 = ((unsigned)(l + 6 - 3 * i) < (unsigned)LEN) ? a2 : 0.f;      \
            }                                                                     \
            x1 += a1; x2 += a2;                                                   \
        }                                                                         \
        s1 += x1; s1q = fmaf(x1, x1, s1q);                                        \
        s2 += x2; s2q = fmaf(x2, x2, s2q);                                        \
        s3 += x3; s3q = fmaf(x3, x3, s3q);                                        \
    }
                if (!edge) { STAT_BODY(false) } else { STAT_BODY(true) }
#undef STAT_BODY

#pragma unroll
                for (int off = 32; off > 0; off >>= 1) {
                    s1 += __shfl_down(s1, off);  s1q += __shfl_down(s1q, off);
                    s2 += __shfl_down(s2, off);  s2q += __shfl_down(s2q, off);
                    s3 += __shfl_down(s3, off);  s3q += __shfl_down(s3q, off);
                }
                const int lane = tid & 63, wvv = tid >> 6;
                if (lane == 0) {
                    red[0][wvv] = s1; red[1][wvv] = s1q;
                    red[2][wvv] = s2; red[3][wvv] = s2q;
                    red[4][wvv] = s3; red[5][wvv] = s3q;
                }
                __syncthreads();
                if (tid < 6) {
                    float t = red[tid][0] + red[tid][1] + red[tid][2] + red[tid][3];
                    stats_put(&stats_ws[(tid * REPN + r) * BATCH + b], t);
                }
            } else {
                // ghost pass-through from the staged buffer (nt store: never re-read)
                const int g = (item - NROW) % GHOSTN;
                const int b = (item - NROW) / GHOSTN;
                f32x4* dst = (f32x4*)(out + ((size_t)b * CH + REPN + g) * LEN);
                const f32x4* sb4 = (const f32x4*)(s[buf] + 8);
#pragma unroll
                for (int t = 0; t < 4; ++t)
                    __builtin_nontemporal_store(sb4[tid + 256 * t], &dst[tid + 256 * t]);
            }

            // T14 write-late: park prefetched regs into the other buffer
            if (k < 7) {
                f32x4* s4 = (f32x4*)(s[buf ^ 1] + 8);
#pragma unroll
                for (int t = 0; t < 4; ++t) s4[tid + 256 * t] = pf[t];
            }
            __syncthreads();
        }
    }

    if constexpr (MODE == 0) {
        // ---- grid-wide barrier: stats complete & visible (agent atomics) ----
        __threadfence();
        cg::this_grid().sync();
    }

    if constexpr (MODE != 1) {
        // ---------------- phase 2: half-row per wave ----------------
        const int wv0 = (blockIdx.x << 2) | (tid >> 6);
        const int lane = tid & 63;

#pragma unroll 1
        for (int u = wv0; u < 2 * NROW; u += 4 * GRID) {
            const int rowid = u >> 1;
            const int half = u & 1;
            const int r = rowid % REPN;
            const int b = rowid / REPN;

            // BN finalize: lanes load the 32 batch partials (dup across halves).
            float p[6];
            const int bb = lane & 31;
#pragma unroll
            for (int q = 0; q < 6; ++q) p[q] = stats_get(&stats_ws[(q * REPN + r) * BATCH + bb]);
#pragma unroll
            for (int m = 1; m < 32; m <<= 1)
#pragma unroll
                for (int q = 0; q < 6; ++q) p[q] += __shfl_xor(p[q], m);

            const double invN = 1.0 / (double)(BATCH * LEN);
            float sc[3], sh[3];
            {
                const float gr[3] = {g1[r], g2[r], g3[r]};
                const float br[3] = {b1[r], b2[r], b3[r]};
#pragma unroll
                for (int q = 0; q < 3; ++q) {
                    double mean = (double)p[2 * q] * invN;
                    double var = (double)p[2 * q + 1] * invN - mean * mean;
                    double inv = 1.0 / sqrt(var + 1e-5);
                    double scale = (double)gr[q] * inv;
                    sc[q] = (float)scale;
                    sh[q] = (float)((double)br[q] - mean * scale);
                }
            }
            const float base = sh[0] + sh[1] + sh[2];

            float wb[5][3];
            {
                const float* p1 = w1 + r * 15;
                const float* p2 = w2 + r * 15;
#pragma unroll
                for (int i = 0; i < 5; ++i)
#pragma unroll
                    for (int t = 0; t < 3; ++t) wb[i][t] = p1[i * 3 + t] + p2[i * 3 + t];
            }
            // Combined 15-tap filter (interior): tap d=3k+t applies to v[j+1+d].
            float c[15];
#pragma unroll
            for (int k = 0; k < 5; ++k)
#pragma unroll
                for (int t = 0; t < 3; ++t)
                    c[3 * k + t] = fmaf(sc[0], wb[k][t], sc[1] * wb[4 - k][t]);
#pragma unroll
            for (int t = 0; t < 3; ++t) c[6 + t] = fmaf(sc[2], wb[2][t], c[6 + t]);

            const float* row = x + ((size_t)b * CH + d_tab.rep[r]) * LEN;
            float* orow = out + ((size_t)b * CH + r) * LEN;
            float v[20];

#define INTERIOR_QUAD(E)                                                          \
    {                                                                             \
        float o[4];                                                               \
        _Pragma("unroll")                                                         \
        for (int j = 0; j < 4; ++j) {                                             \
            float acc = base + v[j + 8];                                          \
            _Pragma("unroll")                                                     \
            for (int d = 0; d < 15; ++d) acc = fmaf(c[d], v[j + 1 + d], acc);     \
            o[j] = acc;                                                           \
        }                                                                         \
        f32x4 t = {o[0], o[1], o[2], o[3]};                                       \
        __builtin_nontemporal_store(t, (f32x4*)(orow + (E)));                     \
    }

#define EDGE_QUAD(E)                                                              \
    {                                                                             \
        float o[4];                                                               \
        _Pragma("unroll")                                                         \
        for (int j = 0; j < 4; ++j) {                                             \
            const int l = (E) + j;                                                \
            float x1 = 0.f, x2 = 0.f, x3 = 0.f;                                   \
            _Pragma("unroll")                                                     \
            for (int i = 0; i < 5; ++i) {                                         \
                float a1 = fmaf(wb[i][0], v[j + 1 + 3 * i],                       \
                           fmaf(wb[i][1], v[j + 2 + 3 * i],                       \
                                wb[i][2] * v[j + 3 + 3 * i]));                    \
                float a2 = fmaf(wb[i][0], v[j + 13 - 3 * i],                      \
                           fmaf(wb[i][1], v[j + 14 - 3 * i],                      \
                                wb[i][2] * v[j + 15 - 3 * i]));                   \
                if (i == 2) x3 = a1;                                              \
                a1 = ((unsigned)(l - 6 + 3 * i) < (unsigned)LEN) ? a1 : 0.f;      \
                a2 = ((unsigned)(l + 6 - 3 * i) < (unsigned)LEN) ? a2 : 0.f;      \
                x1 += a1; x2 += a2;                                               \
            }                                                                     \
            o[j] = fmaf(sc[0], x1, fmaf(sc[1], x2, fmaf(sc[2], x3, base + v[j + 8]))); \
        }                                                                         \
        f32x4 t = {o[0], o[1], o[2], o[3]};                                       \
        __builtin_nontemporal_store(t, (f32x4*)(orow + (E)));                     \
    }

            if (half == 0) {
                { // k = 0: lanes 0,1 touch the left edge (l < 6)
                    const int e = 4 * lane;
                    if (lane < 2) { load_slow(row, e, v); EDGE_QUAD(e); }
                    else          { load_fast(row, e, v); INTERIOR_QUAD(e); }
                }
#pragma unroll
                for (int k = 1; k < 8; ++k) {
                    const int e = 4 * lane + 256 * k;
                    load_fast(row, e, v);
                    INTERIOR_QUAD(e);
                }
            } else {
#pragma unroll
                for (int k = 0; k < 7; ++k) {
                    const int e = 2048 + 4 * lane + 256 * k;
                    load_fast(row, e, v);
                    INTERIOR_QUAD(e);
                }
                { // last quad-group: lanes 62,63 touch the right edge (l >= 4090)
                    const int e = 3840 + 4 * lane;
                    if (lane >= 62) { load_slow(row, e, v); EDGE_QUAD(e); }
                    else            { load_fast(row, e, v); INTERIOR_QUAD(e); }
                }
            }
#undef INTERIOR_QUAD
#undef EDGE_QUAD
        }
    }
}

extern "C" void kernel_launch(void* const* d_in, const int* in_sizes, int n_in,
                              void* d_out, int out_size, void* d_ws, size_t ws_size,
                              hipStream_t stream) {
    const float* x  = (const float*)d_in[0];
    const float* w1 = (const float*)d_in[1];
    const float* w2 = (const float*)d_in[2];
    const float* g1 = (const float*)d_in[3];
    const float* b1 = (const float*)d_in[4];
    const float* g2 = (const float*)d_in[5];
    const float* b2 = (const float*)d_in[6];
    const float* g3 = (const float*)d_in[7];
    const float* b3 = (const float*)d_in[8];
    float* out = (float*)d_out;
    float* stats_ws = (float*)d_ws;   // 6*198*32 floats = 152 KB

    void* args[] = {(void*)&x, (void*)&w1, (void*)&w2, (void*)&stats_ws,
                    (void*)&g1, (void*)&b1, (void*)&g2, (void*)&b2,
                    (void*)&g3, (void*)&b3, (void*)&out};
    // Cooperative: 1024 blocks x 256 thr; __launch_bounds__(256,4) caps VGPR
    // at 128, LDS 33 KB/block -> 4 blocks/CU -> exactly 1024 co-resident.
    hipError_t e = hipLaunchCooperativeKernel(
        reinterpret_cast<void*>(&fused_kernel<0>), dim3(GRID), dim3(256),
        args, 0, stream);
    if (e != hipSuccess) {
        // Fallback: two normal launches; the dispatch boundary provides the
        // stats_ws coherence that grid.sync cannot.
        fused_kernel<1><<<GRID, 256, 0, stream>>>(x, w1, w2, stats_ws,
                                                  g1, b1, g2, b2, g3, b3, out);
        fused_kernel<2><<<GRID, 256, 0, stream>>>(x, w1, w2, stats_ws,
                                                  g1, b1, g2, b2, g3, b3, out);
    }
}

// Round 3
// 212.994 us; speedup vs baseline: 1.9081x; 1.9081x over previous
//
#include <hip/hip_runtime.h>

#define LEN 4096
#define BATCH 32
#define CH 256
#define REPN 198
#define GHOSTN 58

typedef float f32x4 __attribute__((ext_vector_type(4)));

// ---------------------------------------------------------------------------
// COMPILE-TIME numpy-legacy RNG replication (verified in prior session):
// np.random.seed(123); np.random.choice(256, 58, replace=False)
// ---------------------------------------------------------------------------
struct MTState { unsigned mt[624]; int mti; };
struct Tab { int rep[REPN]; int ghost[GHOSTN]; };

static constexpr unsigned mt_next(MTState& s) {
    if (s.mti >= 624) {
        for (int k = 0; k < 624; ++k) {
            unsigned y = (s.mt[k] & 0x80000000u) | (s.mt[(k + 1) % 624] & 0x7fffffffu);
            s.mt[k] = s.mt[(k + 397) % 624] ^ (y >> 1) ^ ((y & 1u) ? 0x9908b0dfu : 0u);
        }
        s.mti = 0;
    }
    unsigned y = s.mt[s.mti++];
    y ^= y >> 11;
    y ^= (y << 7) & 0x9d2c5680u;
    y ^= (y << 15) & 0xefc60000u;
    y ^= y >> 18;
    return y;
}

static constexpr Tab make_tab() {
    MTState s{};
    s.mt[0] = 123u;
    for (int i = 1; i < 624; ++i)
        s.mt[i] = 1812433253u * (s.mt[i - 1] ^ (s.mt[i - 1] >> 30)) + (unsigned)i;
    s.mti = 624;
    int perm[256] = {};
    for (int i = 0; i < 256; ++i) perm[i] = i;
    for (int i = 255; i > 0; --i) {
        unsigned mask = (unsigned)i;
        mask |= mask >> 1; mask |= mask >> 2; mask |= mask >> 4;
        mask |= mask >> 8; mask |= mask >> 16;
        unsigned j = 0;
        do { j = mt_next(s) & mask; } while (j > (unsigned)i);
        int t = perm[i]; perm[i] = perm[j]; perm[j] = t;
    }
    bool g[256] = {};
    for (int k = 0; k < GHOSTN; ++k) g[perm[k]] = true;
    Tab t{};
    int rc = 0, gc = 0;
    for (int c = 0; c < 256; ++c) {
        if (g[c]) t.ghost[gc++] = c;
        else      t.rep[rc++] = c;
    }
    return t;
}

__constant__ Tab d_tab = make_tab();

// ---------------------------------------------------------------------------
// Overlapping-window loads (verified pass-2 pattern): v[d] = row[e-8+d], d<20.
// Consecutive lanes overlap 80B windows at 16B stride -> L1 absorbs the 5x.
// ---------------------------------------------------------------------------
__device__ __forceinline__ void load_fast(const float* __restrict__ row, int e, float* v) {
    const f32x4* q4 = (const f32x4*)(row + e - 8);
#pragma unroll
    for (int t = 0; t < 5; ++t) {
        f32x4 u = q4[t];
        v[4 * t] = u.x; v[4 * t + 1] = u.y; v[4 * t + 2] = u.z; v[4 * t + 3] = u.w;
    }
}

__device__ __forceinline__ void load_slow(const float* __restrict__ row, int e, float* v) {
#pragma unroll
    for (int d = 0; d < 20; ++d) {
        int fi = e - 8 + d;
        v[d] = ((unsigned)fi < (unsigned)LEN) ? row[fi] : 0.f;
    }
}

// ===========================================================================
// Mono-kernel: ONE normal dispatch, zero cross-block communication.
//   blocks 0..197   : rep channel r. 1024 thr = 16 waves; wave wv handles
//                     batches {2wv, 2wv+1}. Stats (FIR sums) in registers ->
//                     one LDS reduce -> BN finalize -> output the same rows
//                     (re-read is L2/L3-hot: the block itself just read them).
//   blocks 198..255 : ghost channel copy (32 rows, nt both ways).
// FIR semantics (verified prior session):
//   x1 group i: taps v[j+1+3i..j+3+3i], gated on 0 <= l-6+3i < LEN
//   x2 group i: taps v[j+13-3i..j+15-3i], gated on 0 <= l+6-3i < LEN
//   x3 = ungated group-2 partial of x1
// ===========================================================================
__global__ __launch_bounds__(1024, 4) void mono_kernel(
    const float* __restrict__ x,
    const float* __restrict__ w1, const float* __restrict__ w2,
    const float* __restrict__ g1, const float* __restrict__ b1,
    const float* __restrict__ g2, const float* __restrict__ b2,
    const float* __restrict__ g3, const float* __restrict__ b3,
    float* __restrict__ out) {
    const int blk = blockIdx.x;
    const int tid = threadIdx.x;

    if (blk >= REPN) {
        // ---------------- ghost pass-through block ----------------
        const int gi = blk - REPN;
        const int ch = d_tab.ghost[gi];
#pragma unroll 1
        for (int b = 0; b < BATCH; ++b) {
            const f32x4* src = (const f32x4*)(x + ((size_t)b * CH + ch) * LEN);
            f32x4* dst = (f32x4*)(out + ((size_t)b * CH + REPN + gi) * LEN);
            f32x4 t = __builtin_nontemporal_load(&src[tid]);
            __builtin_nontemporal_store(t, &dst[tid]);
        }
        return;
    }

    // ---------------- rep channel block ----------------
    __shared__ float red[6][16];
    const int r = blk;
    const int ch = d_tab.rep[r];
    const int wv = tid >> 6;
    const int lane = tid & 63;

    // filter weights
    float wb[5][3];
    {
        const float* p1 = w1 + r * 15;
        const float* p2 = w2 + r * 15;
#pragma unroll
        for (int i = 0; i < 5; ++i)
#pragma unroll
            for (int t = 0; t < 3; ++t) wb[i][t] = p1[i * 3 + t] + p2[i * 3 + t];
    }

    // ---- phase A: stats over this wave's 2 batch rows ----
    float s1 = 0, s1q = 0, s2 = 0, s2q = 0, s3 = 0, s3q = 0;
    float v[20];

#define STATQ(E, GATED)                                                           \
    {                                                                             \
        _Pragma("unroll")                                                         \
        for (int j = 0; j < 4; ++j) {                                             \
            const int l = (E) + j;                                                \
            float x1 = 0.f, x2 = 0.f, x3 = 0.f;                                   \
            _Pragma("unroll")                                                     \
            for (int i = 0; i < 5; ++i) {                                         \
                float a1 = fmaf(wb[i][0], v[j + 1 + 3 * i],                       \
                           fmaf(wb[i][1], v[j + 2 + 3 * i],                       \
                                wb[i][2] * v[j + 3 + 3 * i]));                    \
                float a2 = fmaf(wb[i][0], v[j + 13 - 3 * i],                      \
                           fmaf(wb[i][1], v[j + 14 - 3 * i],                      \
                                wb[i][2] * v[j + 15 - 3 * i]));                   \
                if (i == 2) x3 = a1; /* ungated */                                \
                if (GATED) {                                                      \
                    a1 = ((unsigned)(l - 6 + 3 * i) < (unsigned)LEN) ? a1 : 0.f;  \
                    a2 = ((unsigned)(l + 6 - 3 * i) < (unsigned)LEN) ? a2 : 0.f;  \
                }                                                                 \
                x1 += a1; x2 += a2;                                               \
            }                                                                     \
            s1 += x1; s1q = fmaf(x1, x1, s1q);                                    \
            s2 += x2; s2q = fmaf(x2, x2, s2q);                                    \
            s3 += x3; s3q = fmaf(x3, x3, s3q);                                    \
        }                                                                         \
    }

#pragma unroll 1
    for (int bb = 0; bb < 2; ++bb) {
        const int b = 2 * wv + bb;
        const float* row = x + ((size_t)b * CH + ch) * LEN;
        { // k = 0: lanes 0,1 contain l < 6
            const int e = 4 * lane;
            if (lane < 2) { load_slow(row, e, v); STATQ(e, true); }
            else          { load_fast(row, e, v); STATQ(e, false); }
        }
#pragma unroll 2
        for (int k = 1; k < 15; ++k) {
            const int e = 4 * lane + 256 * k;
            load_fast(row, e, v);
            STATQ(e, false);
        }
        { // k = 15: lanes 62,63 contain l >= 4090
            const int e = 4 * lane + 3840;
            if (lane >= 62) { load_slow(row, e, v); STATQ(e, true); }
            else            { load_fast(row, e, v); STATQ(e, false); }
        }
    }
#undef STATQ

    // wave reduce (64 lanes)
#pragma unroll
    for (int off = 32; off > 0; off >>= 1) {
        s1 += __shfl_down(s1, off);  s1q += __shfl_down(s1q, off);
        s2 += __shfl_down(s2, off);  s2q += __shfl_down(s2q, off);
        s3 += __shfl_down(s3, off);  s3q += __shfl_down(s3q, off);
    }
    if (lane == 0) {
        red[0][wv] = s1; red[1][wv] = s1q;
        red[2][wv] = s2; red[3][wv] = s2q;
        red[4][wv] = s3; red[5][wv] = s3q;
    }
    __syncthreads();

    // ---- BN finalize (every thread; broadcast LDS reads) ----
    float p[6];
#pragma unroll
    for (int q = 0; q < 6; ++q) {
        float t = 0.f;
#pragma unroll
        for (int wvi = 0; wvi < 16; ++wvi) t += red[q][wvi];
        p[q] = t;
    }
    const double invN = 1.0 / (double)(BATCH * LEN);
    float sc[3], sh[3];
    {
        const float gr[3] = {g1[r], g2[r], g3[r]};
        const float br[3] = {b1[r], b2[r], b3[r]};
#pragma unroll
        for (int q = 0; q < 3; ++q) {
            double mean = (double)p[2 * q] * invN;
            double var = (double)p[2 * q + 1] * invN - mean * mean;
            double inv = 1.0 / sqrt(var + 1e-5);
            double scale = (double)gr[q] * inv;
            sc[q] = (float)scale;
            sh[q] = (float)((double)br[q] - mean * scale);
        }
    }
    const float base = sh[0] + sh[1] + sh[2];

    // Combined 15-tap filter (interior): tap d=3k+t applies to v[j+1+d].
    float c[15];
#pragma unroll
    for (int k = 0; k < 5; ++k)
#pragma unroll
        for (int t = 0; t < 3; ++t)
            c[3 * k + t] = fmaf(sc[0], wb[k][t], sc[1] * wb[4 - k][t]);
#pragma unroll
    for (int t = 0; t < 3; ++t) c[6 + t] = fmaf(sc[2], wb[2][t], c[6 + t]);

    // ---- phase B: output this wave's 2 rows (rows are L2/L3-hot) ----
#define INTERIOR_QUAD(E)                                                          \
    {                                                                             \
        float o[4];                                                               \
        _Pragma("unroll")                                                         \
        for (int j = 0; j < 4; ++j) {                                             \
            float acc = base + v[j + 8];                                          \
            _Pragma("unroll")                                                     \
            for (int d = 0; d < 15; ++d) acc = fmaf(c[d], v[j + 1 + d], acc);     \
            o[j] = acc;                                                           \
        }                                                                         \
        f32x4 t = {o[0], o[1], o[2], o[3]};                                       \
        __builtin_nontemporal_store(t, (f32x4*)(orow + (E)));                     \
    }

#define EDGE_QUAD(E)                                                              \
    {                                                                             \
        float o[4];                                                               \
        _Pragma("unroll")                                                         \
        for (int j = 0; j < 4; ++j) {                                             \
            const int l = (E) + j;                                                \
            float x1 = 0.f, x2 = 0.f, x3 = 0.f;                                   \
            _Pragma("unroll")                                                     \
            for (int i = 0; i < 5; ++i) {                                         \
                float a1 = fmaf(wb[i][0], v[j + 1 + 3 * i],                       \
                           fmaf(wb[i][1], v[j + 2 + 3 * i],                       \
                                wb[i][2] * v[j + 3 + 3 * i]));                    \
                float a2 = fmaf(wb[i][0], v[j + 13 - 3 * i],                      \
                           fmaf(wb[i][1], v[j + 14 - 3 * i],                      \
                                wb[i][2] * v[j + 15 - 3 * i]));                   \
                if (i == 2) x3 = a1;                                              \
                a1 = ((unsigned)(l - 6 + 3 * i) < (unsigned)LEN) ? a1 : 0.f;      \
                a2 = ((unsigned)(l + 6 - 3 * i) < (unsigned)LEN) ? a2 : 0.f;      \
                x1 += a1; x2 += a2;                                               \
            }                                                                     \
            o[j] = fmaf(sc[0], x1, fmaf(sc[1], x2, fmaf(sc[2], x3, base + v[j + 8]))); \
        }                                                                         \
        f32x4 t = {o[0], o[1], o[2], o[3]};                                       \
        __builtin_nontemporal_store(t, (f32x4*)(orow + (E)));                     \
    }

#pragma unroll 1
    for (int bb = 0; bb < 2; ++bb) {
        const int b = 2 * wv + bb;
        const float* row = x + ((size_t)b * CH + ch) * LEN;
        float* orow = out + ((size_t)b * CH + r) * LEN;
        { // k = 0
            const int e = 4 * lane;
            if (lane < 2) { load_slow(row, e, v); EDGE_QUAD(e); }
            else          { load_fast(row, e, v); INTERIOR_QUAD(e); }
        }
#pragma unroll
        for (int k = 1; k < 15; ++k) {
            const int e = 4 * lane + 256 * k;
            load_fast(row, e, v);
            INTERIOR_QUAD(e);
        }
        { // k = 15
            const int e = 4 * lane + 3840;
            if (lane >= 62) { load_slow(row, e, v); EDGE_QUAD(e); }
            else            { load_fast(row, e, v); INTERIOR_QUAD(e); }
        }
    }
#undef INTERIOR_QUAD
#undef EDGE_QUAD
}

extern "C" void kernel_launch(void* const* d_in, const int* in_sizes, int n_in,
                              void* d_out, int out_size, void* d_ws, size_t ws_size,
                              hipStream_t stream) {
    const float* x  = (const float*)d_in[0];
    const float* w1 = (const float*)d_in[1];
    const float* w2 = (const float*)d_in[2];
    const float* g1 = (const float*)d_in[3];
    const float* b1 = (const float*)d_in[4];
    const float* g2 = (const float*)d_in[5];
    const float* b2 = (const float*)d_in[6];
    const float* g3 = (const float*)d_in[7];
    const float* b3 = (const float*)d_in[8];
    float* out = (float*)d_out;

    // One normal dispatch: 198 rep-channel blocks + 58 ghost blocks = 256
    // blocks (one per CU), 1024 threads each. No workspace, no atomics,
    // no grid sync -> no cross-XCD coherence surface.
    mono_kernel<<<REPN + GHOSTN, 1024, 0, stream>>>(x, w1, w2,
                                                    g1, b1, g2, b2, g3, b3, out);
}

// Round 4
// 96.360 us; speedup vs baseline: 4.2176x; 2.2104x over previous
//
#include <hip/hip_runtime.h>
#include <hip/hip_bf16.h>

#define LEN 4096
#define BATCH 32
#define CH 256
#define REPN 198
#define GHOSTN 58
#define NROW (REPN * BATCH)     /* 6336 */
#define NGHOST (GHOSTN * BATCH) /* 1856 */
#define CPT 16                  /* outputs per thread in pass1 */

typedef float f32x4 __attribute__((ext_vector_type(4)));

// ---------------------------------------------------------------------------
// COMPILE-TIME numpy-legacy RNG replication (verified rounds 1-8):
// np.random.seed(123); np.random.choice(256, 58, replace=False)
// ---------------------------------------------------------------------------
struct MTState { unsigned mt[624]; int mti; };
struct Tab { int rep[REPN]; int ghost[GHOSTN]; };

static constexpr unsigned mt_next(MTState& s) {
    if (s.mti >= 624) {
        for (int k = 0; k < 624; ++k) {
            unsigned y = (s.mt[k] & 0x80000000u) | (s.mt[(k + 1) % 624] & 0x7fffffffu);
            s.mt[k] = s.mt[(k + 397) % 624] ^ (y >> 1) ^ ((y & 1u) ? 0x9908b0dfu : 0u);
        }
        s.mti = 0;
    }
    unsigned y = s.mt[s.mti++];
    y ^= y >> 11;
    y ^= (y << 7) & 0x9d2c5680u;
    y ^= (y << 15) & 0xefc60000u;
    y ^= y >> 18;
    return y;
}

static constexpr Tab make_tab() {
    MTState s{};
    s.mt[0] = 123u;
    for (int i = 1; i < 624; ++i)
        s.mt[i] = 1812433253u * (s.mt[i - 1] ^ (s.mt[i - 1] >> 30)) + (unsigned)i;
    s.mti = 624;
    int perm[256] = {};
    for (int i = 0; i < 256; ++i) perm[i] = i;
    for (int i = 255; i > 0; --i) {
        unsigned mask = (unsigned)i;
        mask |= mask >> 1; mask |= mask >> 2; mask |= mask >> 4;
        mask |= mask >> 8; mask |= mask >> 16;
        unsigned j = 0;
        do { j = mt_next(s) & mask; } while (j > (unsigned)i);
        int t = perm[i]; perm[i] = perm[j]; perm[j] = t;
    }
    bool g[256] = {};
    for (int k = 0; k < GHOSTN; ++k) g[perm[k]] = true;
    Tab t{};
    int rc = 0, gc = 0;
    for (int c = 0; c < 256; ++c) {
        if (g[c]) t.ghost[gc++] = c;
        else      t.rep[rc++] = c;
    }
    return t;
}

__constant__ Tab d_tab = make_tab();

// ===========================================================================
// Pass 1 — LDS-staged stats, block per rep row (r1/r4 structure). Ghost copy
// rides along as extra blocks. ONE CHANGE vs the 95.7us baseline: all output
// stores are PLAIN cached stores (NT 16B stores measured 2.6x HBM write
// amplification in R2/R3 counters: WRITE 348-424 MB vs 134 MB output).
// ===========================================================================
__global__ __launch_bounds__(256) void pass1_kernel(const float* __restrict__ x,
                                                    const float* __restrict__ w1,
                                                    const float* __restrict__ w2,
                                                    float* __restrict__ stats_ws,
                                                    float* __restrict__ out) {
    const int blk = blockIdx.x;
    if (blk >= NROW) {
        // ghost pass-through: NT load (never re-read), PLAIN store
        const int g = (blk - NROW) % GHOSTN;
        const int b = (blk - NROW) / GHOSTN;
        const int ch = d_tab.ghost[g];
        const f32x4* src = (const f32x4*)(x + ((size_t)b * CH + ch) * LEN);
        f32x4* dst = (f32x4*)(out + ((size_t)b * CH + REPN + g) * LEN);
#pragma unroll
        for (int k = 0; k < 4; ++k) {
            f32x4 t = __builtin_nontemporal_load(&src[threadIdx.x + 256 * k]);
            dst[threadIdx.x + 256 * k] = t;
        }
        return;
    }
    __shared__ float s[LEN + 16];
    __shared__ float red[6][4];
    const int r = blk % REPN;
    const int b = blk / REPN;
    const int ch = d_tab.rep[r];
    const float* row = x + ((size_t)b * CH + ch) * LEN;

    // Coalesced stage: s[8 + l] = row[l]; zero 8-float halos.
    {
        const f32x4* row4 = (const f32x4*)row;
        f32x4* s4 = (f32x4*)(s + 8);
#pragma unroll
        for (int k = 0; k < 4; ++k) s4[threadIdx.x + 256 * k] = row4[threadIdx.x + 256 * k];
        if (threadIdx.x < 8) { s[threadIdx.x] = 0.f; s[LEN + 8 + threadIdx.x] = 0.f; }
    }

    float w[5][3];
    const float* p1 = w1 + r * 15;
    const float* p2 = w2 + r * 15;
#pragma unroll
    for (int i = 0; i < 5; ++i)
#pragma unroll
        for (int t = 0; t < 3; ++t) w[i][t] = p1[i * 3 + t] + p2[i * 3 + t];
    __syncthreads();

    const int l0 = threadIdx.x * CPT;
    // Thread window: v[k] = row[l0 - 8 + k], 16B-aligned ds_read_b128 x8.
    float v[32];
    {
        const f32x4* sw = (const f32x4*)(s + l0);
#pragma unroll
        for (int k = 0; k < 8; ++k) {
            f32x4 t = sw[k];
            v[4 * k] = t.x; v[4 * k + 1] = t.y; v[4 * k + 2] = t.z; v[4 * k + 3] = t.w;
        }
    }

    // FIR semantics (verified rounds 1-8):
    //   x1 group i: taps v[j+1+3i..j+3+3i], gated on 0 <= l-6+3i < LEN
    //   x2 group i: taps v[j+13-3i..j+15-3i], gated on 0 <= l+6-3i < LEN
    //   x3 = ungated group-2 partial of x1
    float s1 = 0, s1q = 0, s2 = 0, s2q = 0, s3 = 0, s3q = 0;
    const bool edge = (threadIdx.x == 0) | (threadIdx.x == 255);
#define STAT_BODY(GATED)                                                          \
    _Pragma("unroll")                                                             \
    for (int j = 0; j < CPT; ++j) {                                               \
        const int l = l0 + j;                                                     \
        float x1 = 0.f, x2 = 0.f, x3 = 0.f;                                       \
        _Pragma("unroll")                                                         \
        for (int i = 0; i < 5; ++i) {                                             \
            float a1 = fmaf(w[i][0], v[j + 1 + 3 * i],                            \
                       fmaf(w[i][1], v[j + 2 + 3 * i],                            \
                            w[i][2] * v[j + 3 + 3 * i]));                         \
            float a2 = fmaf(w[i][0], v[j + 13 - 3 * i],                           \
                       fmaf(w[i][1], v[j + 14 - 3 * i],                           \
                            w[i][2] * v[j + 15 - 3 * i]));                        \
            if (i == 2) x3 = a1; /* ungated */                                    \
            if (GATED) {                                                          \
                a1 = ((unsigned)(l - 6 + 3 * i) < (unsigned)LEN) ? a1 : 0.f;      \
                a2 = ((unsigned)(l + 6 - 3 * i) < (unsigned)LEN) ? a2 : 0.f;      \
            }                                                                     \
            x1 += a1; x2 += a2;                                                   \
        }                                                                         \
        s1 += x1; s1q = fmaf(x1, x1, s1q);                                        \
        s2 += x2; s2q = fmaf(x2, x2, s2q);                                        \
        s3 += x3; s3q = fmaf(x3, x3, s3q);                                        \
    }
    if (!edge) { STAT_BODY(false) } else { STAT_BODY(true) }
#undef STAT_BODY

#pragma unroll
    for (int off = 32; off > 0; off >>= 1) {
        s1 += __shfl_down(s1, off);  s1q += __shfl_down(s1q, off);
        s2 += __shfl_down(s2, off);  s2q += __shfl_down(s2q, off);
        s3 += __shfl_down(s3, off);  s3q += __shfl_down(s3q, off);
    }
    const int lane = threadIdx.x & 63, wv = threadIdx.x >> 6;
    if (lane == 0) {
        red[0][wv] = s1; red[1][wv] = s1q;
        red[2][wv] = s2; red[3][wv] = s2q;
        red[4][wv] = s3; red[5][wv] = s3q;
    }
    __syncthreads();
    if (threadIdx.x < 6) {
        float t = red[threadIdx.x][0] + red[threadIdx.x][1] +
                  red[threadIdx.x][2] + red[threadIdx.x][3];
        stats_ws[(threadIdx.x * REPN + r) * BATCH + b] = t;
    }
}

// ===========================================================================
// Pass 2 — barrier-free wave-per-row, rep rows ONLY (r5 structure). Plain
// cached reads, PLAIN stores (was NT — see amplification note above).
// ===========================================================================
__device__ __forceinline__ void load_fast(const float* __restrict__ row, int e, float* v) {
    const f32x4* q4 = (const f32x4*)(row + e - 8);
#pragma unroll
    for (int t = 0; t < 5; ++t) {
        f32x4 u = q4[t];
        v[4 * t] = u.x; v[4 * t + 1] = u.y; v[4 * t + 2] = u.z; v[4 * t + 3] = u.w;
    }
}

__device__ __forceinline__ void load_slow(const float* __restrict__ row, int e, float* v) {
#pragma unroll
    for (int d = 0; d < 20; ++d) {
        int fi = e - 8 + d;
        v[d] = ((unsigned)fi < (unsigned)LEN) ? row[fi] : 0.f;
    }
}

__global__ __launch_bounds__(256) void pass2_kernel(const float* __restrict__ x,
                                                    const float* __restrict__ w1,
                                                    const float* __restrict__ w2,
                                                    const float* __restrict__ stats_ws,
                                                    const float* __restrict__ g1, const float* __restrict__ b1,
                                                    const float* __restrict__ g2, const float* __restrict__ b2,
                                                    const float* __restrict__ g3, const float* __restrict__ b3,
                                                    float* __restrict__ out) {
    const int wv = (blockIdx.x << 2) | (threadIdx.x >> 6);
    const int lane = threadIdx.x & 63;
    const int r = wv % REPN;
    const int b = wv / REPN;
    const int ch = d_tab.rep[r];
    const float* row = x + ((size_t)b * CH + ch) * LEN;

    // BN finalize: lanes load the 32 batch partials (dup across halves), butterfly.
    float p[6];
    const int bb = lane & 31;
#pragma unroll
    for (int q = 0; q < 6; ++q) p[q] = stats_ws[(q * REPN + r) * BATCH + bb];
#pragma unroll
    for (int m = 1; m < 32; m <<= 1)
#pragma unroll
        for (int q = 0; q < 6; ++q) p[q] += __shfl_xor(p[q], m);

    const double invN = 1.0 / (double)(BATCH * LEN);
    float sc[3], sh[3];
    {
        const float gr[3] = {g1[r], g2[r], g3[r]};
        const float br[3] = {b1[r], b2[r], b3[r]};
#pragma unroll
        for (int q = 0; q < 3; ++q) {
            double mean = (double)p[2 * q] * invN;
            double var = (double)p[2 * q + 1] * invN - mean * mean;
            double inv = 1.0 / sqrt(var + 1e-5);
            double scale = (double)gr[q] * inv;
            sc[q] = (float)scale;
            sh[q] = (float)((double)br[q] - mean * scale);
        }
    }
    const float base = sh[0] + sh[1] + sh[2];

    float wb[5][3];
    const float* p1 = w1 + r * 15;
    const float* p2 = w2 + r * 15;
#pragma unroll
    for (int i = 0; i < 5; ++i)
#pragma unroll
        for (int t = 0; t < 3; ++t) wb[i][t] = p1[i * 3 + t] + p2[i * 3 + t];

    // Combined 15-tap filter (interior): tap d=3k+t applies to v[j+1+d].
    float c[15];
#pragma unroll
    for (int k = 0; k < 5; ++k)
#pragma unroll
        for (int t = 0; t < 3; ++t)
            c[3 * k + t] = fmaf(sc[0], wb[k][t], sc[1] * wb[4 - k][t]);
#pragma unroll
    for (int t = 0; t < 3; ++t) c[6 + t] = fmaf(sc[2], wb[2][t], c[6 + t]);

    float* orow = out + ((size_t)b * CH + r) * LEN;
    float v[20];

#define INTERIOR_QUAD(E)                                                          \
    {                                                                             \
        float o[4];                                                               \
        _Pragma("unroll")                                                         \
        for (int j = 0; j < 4; ++j) {                                             \
            float acc = base + v[j + 8];                                          \
            _Pragma("unroll")                                                     \
            for (int d = 0; d < 15; ++d) acc = fmaf(c[d], v[j + 1 + d], acc);     \
            o[j] = acc;                                                           \
        }                                                                         \
        f32x4 t = {o[0], o[1], o[2], o[3]};                                       \
        *(f32x4*)(orow + (E)) = t;                                                \
    }

#define EDGE_QUAD(E)                                                              \
    {                                                                             \
        float o[4];                                                               \
        _Pragma("unroll")                                                         \
        for (int j = 0; j < 4; ++j) {                                             \
            const int l = (E) + j;                                                \
            float x1 = 0.f, x2 = 0.f, x3 = 0.f;                                   \
            _Pragma("unroll")                                                     \
            for (int i = 0; i < 5; ++i) {                                         \
                float a1 = fmaf(wb[i][0], v[j + 1 + 3 * i],                       \
                           fmaf(wb[i][1], v[j + 2 + 3 * i],                       \
                                wb[i][2] * v[j + 3 + 3 * i]));                    \
                float a2 = fmaf(wb[i][0], v[j + 13 - 3 * i],                      \
                           fmaf(wb[i][1], v[j + 14 - 3 * i],                      \
                                wb[i][2] * v[j + 15 - 3 * i]));                   \
                if (i == 2) x3 = a1;                                              \
                a1 = ((unsigned)(l - 6 + 3 * i) < (unsigned)LEN) ? a1 : 0.f;      \
                a2 = ((unsigned)(l + 6 - 3 * i) < (unsigned)LEN) ? a2 : 0.f;      \
                x1 += a1; x2 += a2;                                               \
            }                                                                     \
            o[j] = fmaf(sc[0], x1, fmaf(sc[1], x2, fmaf(sc[2], x3, base + v[j + 8]))); \
        }                                                                         \
        f32x4 t = {o[0], o[1], o[2], o[3]};                                       \
        *(f32x4*)(orow + (E)) = t;                                                \
    }

    { // k = 0
        const int e = 4 * lane;
        if (lane < 2) { load_slow(row, e, v); EDGE_QUAD(e); }
        else          { load_fast(row, e, v); INTERIOR_QUAD(e); }
    }
#pragma unroll
    for (int k = 1; k < 15; ++k) {
        const int e = 4 * lane + 256 * k;
        load_fast(row, e, v);
        INTERIOR_QUAD(e);
    }
    { // k = 15
        const int e = 4 * lane + 3840;
        if (lane >= 62) { load_slow(row, e, v); EDGE_QUAD(e); }
        else            { load_fast(row, e, v); INTERIOR_QUAD(e); }
    }
#undef INTERIOR_QUAD
#undef EDGE_QUAD
}

extern "C" void kernel_launch(void* const* d_in, const int* in_sizes, int n_in,
                              void* d_out, int out_size, void* d_ws, size_t ws_size,
                              hipStream_t stream) {
    const float* x  = (const float*)d_in[0];
    const float* w1 = (const float*)d_in[1];
    const float* w2 = (const float*)d_in[2];
    const float* g1 = (const float*)d_in[3];
    const float* b1 = (const float*)d_in[4];
    const float* g2 = (const float*)d_in[5];
    const float* b2 = (const float*)d_in[6];
    const float* g3 = (const float*)d_in[7];
    const float* b3 = (const float*)d_in[8];
    float* out = (float*)d_out;
    float* stats_ws = (float*)d_ws;   // 6*198*32 floats = 152 KB

    // pass1: 6336 rep blocks (LDS stats) + 1856 ghost copy blocks.
    pass1_kernel<<<NROW + NGHOST, 256, 0, stream>>>(x, w1, w2, stats_ws, out);
    // pass2: 6336 rep waves = 1584 blocks (barrier-free, plain stores).
    pass2_kernel<<<1584, 256, 0, stream>>>(x, w1, w2, stats_ws,
                                           g1, b1, g2, b2, g3, b3, out);
}